// Round 3
// 423.083 us; speedup vs baseline: 1.2378x; 1.2378x over previous
//
#include <hip/hip_runtime.h>
#include <stdint.h>

typedef unsigned short u16;
typedef unsigned int u32;

#define NV 400000
#define KOFF 27
#define EPS_BN 1e-5f

#define INV_ELEMS (KOFF * NV)            // 10.8M
#define INV_BYTES (INV_ELEMS * 4)        // 43.2 MB
#define FEATSBF_OFF INV_BYTES            // bf16 feats: 51.2 MB
#define WT_OFF (FEATSBF_OFF + NV * 64 * 2)
#define STATS_OFF (WT_OFF + KOFF * 64 * 64 * 2)

using short8 = __attribute__((ext_vector_type(8))) short;
using floatx16 = __attribute__((ext_vector_type(16))) float;

__device__ __forceinline__ u16 f2bf(float f) {
  u32 u = __float_as_uint(f);
  u += 0x7FFFu + ((u >> 16) & 1u);
  return (u16)(u >> 16);
}

// ---------------- init: inv = -1, stats = 0 ----------------
__global__ void k_init(int* __restrict__ inv, float* __restrict__ stats) {
  int i = blockIdx.x * 256 + threadIdx.x;
  if (i < INV_ELEMS / 4) ((int4*)inv)[i] = make_int4(-1, -1, -1, -1);
  if (blockIdx.x == 0) stats[threadIdx.x] = 0.0f;  // sum[64], sq[64], scale[64], shift[64]
}

// ---------------- convert feats fp32 -> bf16 ----------------
__global__ void k_cvt(const float* __restrict__ feats, u16* __restrict__ featsBf) {
  int i = blockIdx.x * 256 + threadIdx.x;   // one float4 per thread
  if (i >= NV * 64 / 4) return;
  float4 v = ((const float4*)feats)[i];
  ushort4 o;
  o.x = f2bf(v.x); o.y = f2bf(v.y); o.z = f2bf(v.z); o.w = f2bf(v.w);
  ((ushort4*)featsBf)[i] = o;
}

// ---------------- build inverse map: inv[k][out_idx] = in_idx ----------------
// within a fixed k, valid out_idx are distinct -> no write conflicts
__global__ void k_build(const int* __restrict__ in_idx, const int* __restrict__ out_idx,
                        const float* __restrict__ mask, int* __restrict__ inv) {
  int t = blockIdx.x * 256 + threadIdx.x;
  if (t >= INV_ELEMS) return;
  if (mask[t] != 0.0f) {
    int k = t / NV;
    inv[k * NV + out_idx[t]] = in_idx[t];
  }
}

// ---------------- transpose+convert W: Wt[k][o][c] = bf16(W[k][c][o]) ----------------
__global__ void k_wt(const float* __restrict__ W, u16* __restrict__ Wt) {
  int t = blockIdx.x * 256 + threadIdx.x;
  if (t >= KOFF * 64 * 64) return;
  int k = t >> 12, rem = t & 4095, c = rem >> 6, o = rem & 63;
  Wt[(k << 12) + (o << 6) + c] = f2bf(W[t]);
}

// ---------------- main: direct-reg gather + 32x32x16 MFMA + fused stats ----------------
// Block = 256 output rows, 4 waves, each wave owns a 64x64 output tile (2x2 of 32x32).
// A fragments are gathered straight from global into MFMA layout (no LDS round-trip);
// W tiles are double-buffered in LDS (reg-staged, one barrier per k).
__global__ void __launch_bounds__(256)
k_main(const u16* __restrict__ feats, const int* __restrict__ inv,
       const u16* __restrict__ Wt, float* __restrict__ out, float* __restrict__ stats) {
  __shared__ u16 Wsm[2][64][72];   // 72-pitch: even bank distribution on frag reads
  __shared__ float redS[4][64];
  __shared__ float redQ[4][64];

  const int t = threadIdx.x;
  const int lane = t & 63;
  const int wave = t >> 6;
  const int lo = lane & 31;        // A row within 32-row group / D col within 32-col group
  const int hi = lane >> 5;        // k-half selector of the fragment
  const int rbase = blockIdx.x * 256 + wave * 64;
  const int row0 = rbase + lo;         // m=0 rows
  const int row1 = rbase + 32 + lo;    // m=1 rows

  const floatx16 z16 = {0.f, 0.f, 0.f, 0.f, 0.f, 0.f, 0.f, 0.f,
                        0.f, 0.f, 0.f, 0.f, 0.f, 0.f, 0.f, 0.f};
  floatx16 acc00 = z16, acc01 = z16, acc10 = z16, acc11 = z16;

  // W staging geometry: 8KB tile = 512 x 16B chunks; thread t stages chunks t and t+256
  const int wr0 = t >> 3;
  const int wc0 = (t & 7) * 8;

  // prologue: prefetch W[0] and src[0]
  uint4 w0 = *(const uint4*)(Wt + t * 8);
  uint4 w1 = *(const uint4*)(Wt + (t + 256) * 8);
  int psrc0 = (row0 < NV) ? inv[row0] : -1;
  int psrc1 = (row1 < NV) ? inv[row1] : -1;

  for (int k = 0; k < KOFF; ++k) {
    const int buf = k & 1;
    // write prefetched W tile into this k's buffer
    *(uint4*)&Wsm[buf][wr0][wc0] = w0;
    *(uint4*)&Wsm[buf][wr0 + 32][wc0] = w1;
    const int src0 = psrc0, src1 = psrc1;
    // prefetch next W tile + next srcs (hides L2/HBM latency under this k's MFMA)
    if (k + 1 < KOFF) {
      const u16* wk = Wt + ((k + 1) << 12);
      w0 = *(const uint4*)(wk + t * 8);
      w1 = *(const uint4*)(wk + (t + 256) * 8);
      const int* ik = inv + (k + 1) * NV;
      psrc0 = (row0 < NV) ? ik[row0] : -1;
      psrc1 = (row1 < NV) ? ik[row1] : -1;
    }
    // gather A straight into MFMA fragment layout; invalid rows exec-masked (no traffic)
    const short8 z8 = {0, 0, 0, 0, 0, 0, 0, 0};
    short8 A0[4], A1[4];
#pragma unroll
    for (int kk = 0; kk < 4; ++kk) { A0[kk] = z8; A1[kk] = z8; }
    if (src0 >= 0) {
      const u16* p = feats + src0 * 64 + hi * 8;
      A0[0] = *(const short8*)(p);
      A0[1] = *(const short8*)(p + 16);
      A0[2] = *(const short8*)(p + 32);
      A0[3] = *(const short8*)(p + 48);
    }
    if (src1 >= 0) {
      const u16* p = feats + src1 * 64 + hi * 8;
      A1[0] = *(const short8*)(p);
      A1[1] = *(const short8*)(p + 16);
      A1[2] = *(const short8*)(p + 32);
      A1[3] = *(const short8*)(p + 48);
    }
    __syncthreads();   // Wsm[buf] writes visible; prior-iter reads of other buffer done
#pragma unroll
    for (int kk = 0; kk < 4; ++kk) {
      short8 b0 = *(const short8*)&Wsm[buf][lo][kk * 16 + hi * 8];
      short8 b1 = *(const short8*)&Wsm[buf][32 + lo][kk * 16 + hi * 8];
      acc00 = __builtin_amdgcn_mfma_f32_32x32x16_bf16(A0[kk], b0, acc00, 0, 0, 0);
      acc01 = __builtin_amdgcn_mfma_f32_32x32x16_bf16(A0[kk], b1, acc01, 0, 0, 0);
      acc10 = __builtin_amdgcn_mfma_f32_32x32x16_bf16(A1[kk], b0, acc10, 0, 0, 0);
      acc11 = __builtin_amdgcn_mfma_f32_32x32x16_bf16(A1[kk], b1, acc11, 0, 0, 0);
    }
  }

  // fused channel stats: lane holds col lo (n=0) / 32+lo (n=1); rows split across hi
  float s0 = 0.f, q0 = 0.f, s1 = 0.f, q1 = 0.f;
#pragma unroll
  for (int r = 0; r < 16; ++r) {
    s0 += acc00[r] + acc10[r];
    q0 += acc00[r] * acc00[r] + acc10[r] * acc10[r];
    s1 += acc01[r] + acc11[r];
    q1 += acc01[r] * acc01[r] + acc11[r] * acc11[r];
  }
  s0 += __shfl_xor(s0, 32, 64); q0 += __shfl_xor(q0, 32, 64);
  s1 += __shfl_xor(s1, 32, 64); q1 += __shfl_xor(q1, 32, 64);
  if (lane < 32) {
    redS[wave][lo] = s0; redQ[wave][lo] = q0;
    redS[wave][32 + lo] = s1; redQ[wave][32 + lo] = q1;
  }

  // epilogue: write pre-BN fp32. D layout: col = lane&31, row = (r&3) + 8*(r>>2) + 4*hi
#pragma unroll
  for (int r = 0; r < 16; ++r) {
    int rl = (r & 3) + ((r >> 2) * 8) + hi * 4;
    int ra = rbase + rl;
    int rb = rbase + 32 + rl;
    if (ra < NV) { out[ra * 64 + lo] = acc00[r]; out[ra * 64 + 32 + lo] = acc01[r]; }
    if (rb < NV) { out[rb * 64 + lo] = acc10[r]; out[rb * 64 + 32 + lo] = acc11[r]; }
  }

  __syncthreads();
  if (t < 64) {
    float s = redS[0][t] + redS[1][t] + redS[2][t] + redS[3][t];
    float q = redQ[0][t] + redQ[1][t] + redQ[2][t] + redQ[3][t];
    atomicAdd(&stats[t], s);
    atomicAdd(&stats[64 + t], q);
  }
}

// ---------------- BN finalize: scale/shift ----------------
__global__ void k_stats(const float* __restrict__ stats, const float* __restrict__ gamma,
                        const float* __restrict__ beta, float* __restrict__ sc,
                        float* __restrict__ sh) {
  int t = threadIdx.x;
  float inv_n = 1.0f / (float)NV;
  float mean = stats[t] * inv_n;
  float var = stats[64 + t] * inv_n - mean * mean;
  float scale = gamma[t] * rsqrtf(var + EPS_BN);
  sc[t] = scale;
  sh[t] = beta[t] - mean * scale;
}

// ---------------- apply BN + ReLU in place (fp32) ----------------
__global__ void k_apply(float* __restrict__ out, const float* __restrict__ sc,
                        const float* __restrict__ sh) {
  int i = blockIdx.x * 256 + threadIdx.x;   // one float4 per thread
  if (i >= NV * 64 / 4) return;
  int c0 = (i & 15) * 4;
  float4 v = ((const float4*)out)[i];
  float* pv = (float*)&v;
#pragma unroll
  for (int j = 0; j < 4; ++j) {
    float y = pv[j] * sc[c0 + j] + sh[c0 + j];
    pv[j] = y > 0.f ? y : 0.f;
  }
  ((float4*)out)[i] = v;
}

extern "C" void kernel_launch(void* const* d_in, const int* in_sizes, int n_in,
                              void* d_out, int out_size, void* d_ws, size_t ws_size,
                              hipStream_t stream) {
  const float* feats = (const float*)d_in[0];
  const float* W     = (const float*)d_in[1];
  const float* gamma = (const float*)d_in[2];
  const float* beta  = (const float*)d_in[3];
  const float* mask  = (const float*)d_in[4];
  const int* in_idx  = (const int*)d_in[5];
  const int* out_idx = (const int*)d_in[6];
  float* out = (float*)d_out;

  char* ws = (char*)d_ws;
  int* inv = (int*)ws;                        // 43.2 MB
  u16* featsBf = (u16*)(ws + FEATSBF_OFF);    // 51.2 MB
  u16* Wt = (u16*)(ws + WT_OFF);              // 216 KB
  float* stats = (float*)(ws + STATS_OFF);    // 256 floats

  k_init<<<(INV_ELEMS / 4 + 255) / 256, 256, 0, stream>>>(inv, stats);
  k_cvt<<<(NV * 64 / 4 + 255) / 256, 256, 0, stream>>>(feats, featsBf);
  k_build<<<(INV_ELEMS + 255) / 256, 256, 0, stream>>>(in_idx, out_idx, mask, inv);
  k_wt<<<(KOFF * 4096 + 255) / 256, 256, 0, stream>>>(W, Wt);
  k_main<<<(NV + 255) / 256, 256, 0, stream>>>(featsBf, inv, Wt, out, stats);
  k_stats<<<1, 64, 0, stream>>>(stats, gamma, beta, stats + 128, stats + 192);
  k_apply<<<(NV * 64 / 4 + 255) / 256, 256, 0, stream>>>(out, stats + 128, stats + 192);
}

// Round 5
// 404.367 us; speedup vs baseline: 1.2951x; 1.0463x over previous
//
#include <hip/hip_runtime.h>
#include <stdint.h>

typedef unsigned short u16;
typedef unsigned int u32;

#define NV 400000
#define KOFF 27
#define EPS_BN 1e-5f

#define INV_ELEMS (KOFF * NV)            // 10.8M
#define INV_BYTES (INV_ELEMS * 4)        // 43.2 MB
#define FEATSBF_OFF INV_BYTES            // bf16 feats: 51.2 MB
#define WT_OFF (FEATSBF_OFF + NV * 64 * 2)
#define STATS_OFF (WT_OFF + KOFF * 64 * 64 * 2)

#define CVT_BLOCKS 25000                 // NV*64/4/256
#define BUILD_BLOCKS 42188               // ceil(INV_ELEMS/256)
#define WT_BLOCKS 432                    // ceil(KOFF*4096/256)
#define PREP_BLOCKS (CVT_BLOCKS + BUILD_BLOCKS + WT_BLOCKS)

using short8 = __attribute__((ext_vector_type(8))) short;
using floatx16 = __attribute__((ext_vector_type(16))) float;

__device__ __forceinline__ u16 f2bf(float f) {
  u32 u = __float_as_uint(f);
  u += 0x7FFFu + ((u >> 16) & 1u);
  return (u16)(u >> 16);
}

// ---------------- fused prep: cvt feats -> bf16 | build inv map | transpose W ----------------
__global__ void k_prep(const float* __restrict__ feats, u16* __restrict__ featsBf,
                       const int* __restrict__ in_idx, const int* __restrict__ out_idx,
                       const float* __restrict__ mask, int* __restrict__ inv,
                       const float* __restrict__ W, u16* __restrict__ Wt) {
  const int b = blockIdx.x;
  const int tid = threadIdx.x;
  if (b < CVT_BLOCKS) {
    // feats fp32 -> bf16, one float4 per thread
    int i = b * 256 + tid;
    float4 v = ((const float4*)feats)[i];
    ushort4 o;
    o.x = f2bf(v.x); o.y = f2bf(v.y); o.z = f2bf(v.z); o.w = f2bf(v.w);
    ((ushort4*)featsBf)[i] = o;
  } else if (b < CVT_BLOCKS + BUILD_BLOCKS) {
    // inverse map: inv[k][out_idx] = in_idx (valid out_idx distinct within k)
    int t = (b - CVT_BLOCKS) * 256 + tid;
    if (t < INV_ELEMS && mask[t] != 0.0f) {
      int k = t / NV;
      inv[k * NV + out_idx[t]] = in_idx[t];
    }
  } else {
    // Wt[k][o][c] = bf16(W[k][c][o])
    int t = (b - CVT_BLOCKS - BUILD_BLOCKS) * 256 + tid;
    if (t < KOFF * 64 * 64) {
      int k = t >> 12, rem = t & 4095, c = rem >> 6, o = rem & 63;
      Wt[(k << 12) + (o << 6) + c] = f2bf(W[t]);
    }
  }
}

// ---------------- main: pipelined reg-gather + 32x32x16 MFMA + fused stats ----------------
// Block = 256 output rows, 4 waves, each wave owns a 64x64 tile (2x2 of 32x32).
// Unroll-by-2 pipeline (parity-named regs, rule #20): at step for tile T we
//   - write T's W tile (prefetched last step) to LDS buf T&1
//   - prefetch W tile T+1 and issue inv srcs for tile T+2
//   - issue the A gather for tile T+1 (consumed after next barrier)
// so gather/inv latency hides under a full MFMA step.
__global__ void __launch_bounds__(256)
k_main(const u16* __restrict__ feats, const int* __restrict__ inv,
       const u16* __restrict__ Wt, float* __restrict__ out, float* __restrict__ stats) {
  __shared__ u16 Wsm[2][64][72];   // 72-pitch: conflict-free frag reads (measured 0)
  __shared__ float redS[4][64];
  __shared__ float redQ[4][64];

  const int t = threadIdx.x;
  const int lane = t & 63;
  const int wave = t >> 6;
  const int lo = lane & 31;        // A row within 32-row group / D col within 32-col group
  const int hi = lane >> 5;        // k-half selector of the fragment
  const int rbase = blockIdx.x * 256 + wave * 64;
  const int row0 = rbase + lo;
  const int row1 = rbase + 32 + lo;
  const bool v0 = row0 < NV;
  const bool v1 = row1 < NV;

  const floatx16 z16 = {0.f, 0.f, 0.f, 0.f, 0.f, 0.f, 0.f, 0.f,
                        0.f, 0.f, 0.f, 0.f, 0.f, 0.f, 0.f, 0.f};
  floatx16 acc00 = z16, acc01 = z16, acc10 = z16, acc11 = z16;

  const int wr0 = t >> 3;
  const int wc0 = (t & 7) * 8;

#define GATHER(A0, A1, s0, s1)                                        \
  {                                                                   \
    const short8 z8 = {0, 0, 0, 0, 0, 0, 0, 0};                       \
    A0[0] = z8; A0[1] = z8; A0[2] = z8; A0[3] = z8;                   \
    A1[0] = z8; A1[1] = z8; A1[2] = z8; A1[3] = z8;                   \
    if ((s0) >= 0) {                                                  \
      const u16* p = feats + (s0) * 64 + hi * 8;                      \
      A0[0] = *(const short8*)(p);                                    \
      A0[1] = *(const short8*)(p + 16);                               \
      A0[2] = *(const short8*)(p + 32);                               \
      A0[3] = *(const short8*)(p + 48);                               \
    }                                                                 \
    if ((s1) >= 0) {                                                  \
      const u16* p = feats + (s1) * 64 + hi * 8;                      \
      A1[0] = *(const short8*)(p);                                    \
      A1[1] = *(const short8*)(p + 16);                               \
      A1[2] = *(const short8*)(p + 32);                               \
      A1[3] = *(const short8*)(p + 48);                               \
    }                                                                 \
  }

#define DOMFMA(BUF, A0, A1)                                                     \
  _Pragma("unroll")                                                             \
  for (int kk = 0; kk < 4; ++kk) {                                              \
    short8 b0 = *(const short8*)&Wsm[BUF][lo][kk * 16 + hi * 8];                \
    short8 b1 = *(const short8*)&Wsm[BUF][32 + lo][kk * 16 + hi * 8];           \
    acc00 = __builtin_amdgcn_mfma_f32_32x32x16_bf16(A0[kk], b0, acc00, 0, 0, 0);\
    acc01 = __builtin_amdgcn_mfma_f32_32x32x16_bf16(A0[kk], b1, acc01, 0, 0, 0);\
    acc10 = __builtin_amdgcn_mfma_f32_32x32x16_bf16(A1[kk], b0, acc10, 0, 0, 0);\
    acc11 = __builtin_amdgcn_mfma_f32_32x32x16_bf16(A1[kk], b1, acc11, 0, 0, 0);\
  }

  // ---- prologue: W tile 0, src tiles 0 and 1, gather A tile 0 ----
  uint4 wEa = *(const uint4*)(Wt + t * 8);
  uint4 wEb = *(const uint4*)(Wt + (t + 256) * 8);
  uint4 wOa = wEa, wOb = wEb;
  int sC0 = v0 ? inv[row0] : -1;
  int sC1 = v1 ? inv[row1] : -1;
  int sO0 = v0 ? inv[NV + row0] : -1;  // src tile 1
  int sO1 = v1 ? inv[NV + row1] : -1;
  int sE0 = -1, sE1 = -1;

  short8 Ac0[4], Ac1[4], An0[4], An1[4];
  GATHER(Ac0, Ac1, sC0, sC1);

  for (int k = 0; k < KOFF; k += 2) {
    // -------- even step: tile k in buf 0 --------
    *(uint4*)&Wsm[0][wr0][wc0] = wEa;
    *(uint4*)&Wsm[0][wr0 + 32][wc0] = wEb;
    if (k + 1 < KOFF) {
      const u16* wk = Wt + ((k + 1) << 12);
      wOa = *(const uint4*)(wk + t * 8);
      wOb = *(const uint4*)(wk + (t + 256) * 8);
    }
    if (k + 2 < KOFF) {
      const int* ik = inv + (k + 2) * NV;
      sE0 = v0 ? ik[row0] : -1;
      sE1 = v1 ? ik[row1] : -1;
    }
    if (k + 1 < KOFF) GATHER(An0, An1, sO0, sO1);   // A for tile k+1
    __syncthreads();
    DOMFMA(0, Ac0, Ac1);
    if (k + 1 >= KOFF) break;
    // -------- odd step: tile k+1 in buf 1 --------
    *(uint4*)&Wsm[1][wr0][wc0] = wOa;
    *(uint4*)&Wsm[1][wr0 + 32][wc0] = wOb;
    if (k + 2 < KOFF) {
      const u16* wk = Wt + ((k + 2) << 12);
      wEa = *(const uint4*)(wk + t * 8);
      wEb = *(const uint4*)(wk + (t + 256) * 8);
    }
    if (k + 3 < KOFF) {
      const int* ik = inv + (k + 3) * NV;
      sO0 = v0 ? ik[row0] : -1;
      sO1 = v1 ? ik[row1] : -1;
    }
    if (k + 2 < KOFF) GATHER(Ac0, Ac1, sE0, sE1);   // A for tile k+2
    __syncthreads();
    DOMFMA(1, An0, An1);
  }
#undef GATHER
#undef DOMFMA

  // fused channel stats: lane holds col lo (n=0) / 32+lo (n=1); rows split across hi
  float s0 = 0.f, q0 = 0.f, s1 = 0.f, q1 = 0.f;
#pragma unroll
  for (int r = 0; r < 16; ++r) {
    s0 += acc00[r] + acc10[r];
    q0 += acc00[r] * acc00[r] + acc10[r] * acc10[r];
    s1 += acc01[r] + acc11[r];
    q1 += acc01[r] * acc01[r] + acc11[r] * acc11[r];
  }
  s0 += __shfl_xor(s0, 32, 64); q0 += __shfl_xor(q0, 32, 64);
  s1 += __shfl_xor(s1, 32, 64); q1 += __shfl_xor(q1, 32, 64);
  if (lane < 32) {
    redS[wave][lo] = s0; redQ[wave][lo] = q0;
    redS[wave][32 + lo] = s1; redQ[wave][32 + lo] = q1;
  }

  // epilogue: write pre-BN fp32. D layout: col = lane&31, row = (r&3) + 8*(r>>2) + 4*hi
#pragma unroll
  for (int r = 0; r < 16; ++r) {
    int rl = (r & 3) + ((r >> 2) * 8) + hi * 4;
    int ra = rbase + rl;
    int rb = rbase + 32 + rl;
    if (ra < NV) { out[ra * 64 + lo] = acc00[r]; out[ra * 64 + 32 + lo] = acc01[r]; }
    if (rb < NV) { out[rb * 64 + lo] = acc10[r]; out[rb * 64 + 32 + lo] = acc11[r]; }
  }

  __syncthreads();
  if (t < 64) {
    float s = redS[0][t] + redS[1][t] + redS[2][t] + redS[3][t];
    float q = redQ[0][t] + redQ[1][t] + redQ[2][t] + redQ[3][t];
    atomicAdd(&stats[t], s);
    atomicAdd(&stats[64 + t], q);
  }
}

// ---------------- apply BN + ReLU in place (stats finalize fused per block) ----------------
__global__ void k_apply(float* __restrict__ out, const float* __restrict__ stats,
                        const float* __restrict__ gamma, const float* __restrict__ beta) {
  __shared__ float sc[64], sh[64];
  const int t = threadIdx.x;
  if (t < 64) {
    float inv_n = 1.0f / (float)NV;
    float mean = stats[t] * inv_n;
    float var = stats[64 + t] * inv_n - mean * mean;
    float scale = gamma[t] * rsqrtf(var + EPS_BN);
    sc[t] = scale;
    sh[t] = beta[t] - mean * scale;
  }
  __syncthreads();
  int i = blockIdx.x * 256 + t;   // one float4 per thread
  if (i >= NV * 64 / 4) return;
  int c0 = (i & 15) * 4;
  float4 v = ((const float4*)out)[i];
  float* pv = (float*)&v;
#pragma unroll
  for (int j = 0; j < 4; ++j) {
    float y = pv[j] * sc[c0 + j] + sh[c0 + j];
    pv[j] = y > 0.f ? y : 0.f;
  }
  ((float4*)out)[i] = v;
}

extern "C" void kernel_launch(void* const* d_in, const int* in_sizes, int n_in,
                              void* d_out, int out_size, void* d_ws, size_t ws_size,
                              hipStream_t stream) {
  const float* feats = (const float*)d_in[0];
  const float* W     = (const float*)d_in[1];
  const float* gamma = (const float*)d_in[2];
  const float* beta  = (const float*)d_in[3];
  const float* mask  = (const float*)d_in[4];
  const int* in_idx  = (const int*)d_in[5];
  const int* out_idx = (const int*)d_in[6];
  float* out = (float*)d_out;

  char* ws = (char*)d_ws;
  int* inv = (int*)ws;                        // 43.2 MB
  u16* featsBf = (u16*)(ws + FEATSBF_OFF);    // 51.2 MB
  u16* Wt = (u16*)(ws + WT_OFF);              // 216 KB
  float* stats = (float*)(ws + STATS_OFF);    // 128 floats used

  hipMemsetAsync(inv, 0xFF, INV_BYTES, stream);              // inv = -1
  hipMemsetAsync(stats, 0, 128 * sizeof(float), stream);     // sum/sq = 0
  k_prep<<<PREP_BLOCKS, 256, 0, stream>>>(feats, featsBf, in_idx, out_idx, mask, inv, W, Wt);
  k_main<<<(NV + 255) / 256, 256, 0, stream>>>(featsBf, inv, Wt, out, stats);
  k_apply<<<NV * 64 / 4 / 256, 256, 0, stream>>>(out, stats, gamma, beta);
}